// Round 18
// baseline (198.806 us; speedup 1.0000x reference)
//
#include <hip/hip_runtime.h>

typedef unsigned short u16;
typedef unsigned int u32;

#define TOKENS 4096   // B*T
#define HDIM 1024
#define IDIM 4096
#define NHEADS 4
#define NKEYS 64
#define TOPK 8
#define QDIM 512      // 2 * NHEADS * 64

typedef __bf16 bf16x8 __attribute__((ext_vector_type(8)));
typedef float  f32x4  __attribute__((ext_vector_type(4)));
typedef float  f32x2  __attribute__((ext_vector_type(2)));
typedef u16    u16x8  __attribute__((ext_vector_type(8)));
typedef u32    u32x4  __attribute__((ext_vector_type(4)));

__device__ __forceinline__ u16 f2bf(float f) {
    u32 u = __float_as_uint(f);
    u += 0x7fffu + ((u >> 16) & 1u);   // RNE
    return (u16)(u >> 16);
}
__device__ __forceinline__ float bf2f(u16 h) { return __uint_as_float(((u32)h) << 16); }

#define H_N4   1048576   // TOKENS*HDIM/4
#define WUP_N4 1048576
#define WDN_N4 1048576
#define DE_N4  1048576
#define UE_N4  1048576
#define CVT_TOT (H_N4 + WUP_N4 + WDN_N4 + DE_N4 + UE_N4)

__device__ __forceinline__ void cvt1(const float* in, u16* hi, u16* lo, int i) {
    float4 v = reinterpret_cast<const float4*>(in)[i];
    float vf[4] = {v.x, v.y, v.z, v.w};
    ushort4 h;
    u16 hh[4];
#pragma unroll
    for (int j = 0; j < 4; j++) hh[j] = f2bf(vf[j]);
    h.x = hh[0]; h.y = hh[1]; h.z = hh[2]; h.w = hh[3];
    reinterpret_cast<ushort4*>(hi)[i] = h;
    if (lo) {
        ushort4 l4;
        u16 ll[4];
#pragma unroll
        for (int j = 0; j < 4; j++) ll[j] = f2bf(vf[j] - bf2f(hh[j]));
        l4.x = ll[0]; l4.y = ll[1]; l4.z = ll[2]; l4.w = ll[3];
        reinterpret_cast<ushort4*>(lo)[i] = l4;
    }
}

__device__ __forceinline__ void cvt1_f8(const float* in, u32* out8, int i) {
    float4 v = reinterpret_cast<const float4*>(in)[i];
    u32 w = __builtin_amdgcn_cvt_pk_fp8_f32(v.x, v.y, 0u, false);
    w = __builtin_amdgcn_cvt_pk_fp8_f32(v.z, v.w, w, true);
    out8[i] = w;
}

// All 5 tensor conversions in one streaming launch.
__global__ __launch_bounds__(256) void cvt_all(
    const float* __restrict__ hidden, const float* __restrict__ W_up,
    const float* __restrict__ W_down, const float* __restrict__ de,
    const float* __restrict__ ue,
    u16* __restrict__ hid_hi, u16* __restrict__ hid_lo,
    u16* __restrict__ wup, u16* __restrict__ wdn,
    u32* __restrict__ de_f8, u32* __restrict__ ue_f8) {
    int i = blockIdx.x * 256 + threadIdx.x;
    if (i >= CVT_TOT) return;
    if (i < H_N4) { cvt1(hidden, hid_hi, hid_lo, i); return; }
    i -= H_N4;
    if (i < WUP_N4) { cvt1(W_up, wup, nullptr, i); return; }
    i -= WUP_N4;
    if (i < WDN_N4) { cvt1(W_down, wdn, nullptr, i); return; }
    i -= WDN_N4;
    if (i < DE_N4) { cvt1_f8(de, de_f8, i); return; }
    i -= DE_N4;
    cvt1_f8(ue, ue_f8, i);
}

// Weff[(p*4+h)*64+k][d] = sum_n keys[h][k][p][n] * Wq[p*256+h*64+n][d],
// fp32 accumulate, split hi/lo bf16 output. Own kernel (R12 lesson).
__global__ __launch_bounds__(256) void weff_kernel(
    const float* __restrict__ keys, const float* __restrict__ Wq,
    u16* __restrict__ weff_hi, u16* __restrict__ weff_lo) {
    __shared__ float kk[64][65];
    __shared__ float wq_s[64][128];

    const int g = blockIdx.x >> 3, ds = blockIdx.x & 7;
    const int p = g >> 2, h = g & 3;
    const int d0 = ds * 128;
    const int t = threadIdx.x;
    const int base = p * 256 + h * 64;

    {
        int k = t >> 2, part = t & 3;
        const float* krow = keys + (((size_t)(h * NKEYS + k) * 2 + p) * 64);
#pragma unroll
        for (int j = 0; j < 4; j++) {
            int n0 = part * 16 + j * 4;
            float4 v = *reinterpret_cast<const float4*>(krow + n0);
            kk[k][n0 + 0] = v.x; kk[k][n0 + 1] = v.y;
            kk[k][n0 + 2] = v.z; kk[k][n0 + 3] = v.w;
        }
    }
    {
        int n = t >> 2, dpart = t & 3;
        const float* wrow = Wq + (size_t)(base + n) * HDIM + d0;
#pragma unroll
        for (int j = 0; j < 8; j++) {
            int dd = dpart * 32 + j * 4;
            float4 v = *reinterpret_cast<const float4*>(wrow + dd);
            *reinterpret_cast<float4*>(&wq_s[n][dd]) = v;
        }
    }
    __syncthreads();

    const int k = t & 63, dq = t >> 6;
    float acc[32];
#pragma unroll
    for (int i = 0; i < 32; i++) acc[i] = 0.f;
    for (int n = 0; n < 64; n++) {
        float kv = kk[k][n];
        const float4* wrow = reinterpret_cast<const float4*>(&wq_s[n][dq * 32]);
#pragma unroll
        for (int j = 0; j < 8; j++) {
            float4 w4 = wrow[j];
            acc[j * 4 + 0] += kv * w4.x; acc[j * 4 + 1] += kv * w4.y;
            acc[j * 4 + 2] += kv * w4.z; acc[j * 4 + 3] += kv * w4.w;
        }
    }
    size_t ro = (size_t)(g * 64 + k) * HDIM + d0 + dq * 32;
#pragma unroll
    for (int j = 0; j < 8; j++) {
        ushort4 hh, ll;
        u16 hv[4], lv[4];
#pragma unroll
        for (int i = 0; i < 4; i++) {
            float a = acc[j * 4 + i];
            hv[i] = f2bf(a);
            lv[i] = f2bf(a - bf2f(hv[i]));
        }
        hh.x = hv[0]; hh.y = hv[1]; hh.z = hv[2]; hh.w = hv[3];
        ll.x = lv[0]; ll.y = lv[1]; ll.z = lv[2]; ll.w = lv[3];
        *reinterpret_cast<ushort4*>(weff_hi + ro + j * 4) = hh;
        *reinterpret_cast<ushort4*>(weff_lo + ro + j * 4) = ll;
    }
}

// out += partial
__global__ __launch_bounds__(256) void reduce_add(float* __restrict__ out,
                                                  const float* __restrict__ p, int n4) {
    int i = blockIdx.x * 256 + threadIdx.x;
    if (i >= n4) return;
    float4 a = reinterpret_cast<const float4*>(out)[i];
    float4 b = reinterpret_cast<const float4*>(p)[i];
    a.x += b.x; a.y += b.y; a.z += b.z; a.w += b.w;
    reinterpret_cast<float4*>(out)[i] = a;
}

__device__ __forceinline__ void gload16(const void* g, void* s) {
    auto gp = reinterpret_cast<const __attribute__((address_space(1))) u32*>(
        reinterpret_cast<uintptr_t>(g));
    auto sp = reinterpret_cast<__attribute__((address_space(3))) u32*>(
        reinterpret_cast<uintptr_t>(s));
    __builtin_amdgcn_global_load_lds(gp, sp, 16, 0, 0);
}

#define BK 32

// LDS rows of 64B; swizzle slot ^= (row>>1)&3 (verified: 0 bank conflicts).
__device__ __forceinline__ int swz(int a) { return a ^ (((a >> 7) & 3) << 4); }

template <int ROWS, int THREADS>
__device__ __forceinline__ void stage_tile(const u16* g, size_t krow_b, size_t kb0,
                                           char* s, int t) {
#pragma unroll
    for (int rnd = 0; rnd < ROWS * 64 / (THREADS * 16); rnd++) {
        int o = t * 16 + rnd * THREADS * 16;
        int os = swz(o);
        int row = o >> 6, kb = os & 63;
        gload16((const char*)g + (size_t)row * krow_b + kb0 + kb, s + o);
    }
}

template <int N>
__device__ __forceinline__ void vm_wait() {
    if constexpr (N == 0) asm volatile("s_waitcnt vmcnt(0)" ::: "memory");
    else if constexpr (N == 3) asm volatile("s_waitcnt vmcnt(3)" ::: "memory");
    else if constexpr (N == 4) asm volatile("s_waitcnt vmcnt(4)" ::: "memory");
    else if constexpr (N == 6) asm volatile("s_waitcnt vmcnt(6)" ::: "memory");
    else if constexpr (N == 8) asm volatile("s_waitcnt vmcnt(8)" ::: "memory");
    else static_assert(N == 0, "unsupported vmcnt");
}

// ---- up-proj body: 256x128 tile, 8 waves (4x2), 3-ring counted vmcnt ----
__device__ void up_body(char* smem, int bx, int by,
                        const u16* __restrict__ A, const u16* __restrict__ B,
                        u16* __restrict__ act, int M, int N, int K) {
    constexpr int LPS = 3;   // (256+128)*64 / (512*16)
    const int t = threadIdx.x;
    const int lane = t & 63;
    const int wave = t >> 6;
    const int wr = wave >> 1, wc = wave & 1;   // 4x2 waves, WM=WN=64
    const int ro = lane & 15;
    const int ko = (lane >> 4) * 16;
    const int m0 = by * 256, n0 = bx * 128;

    f32x4 acc[4][4];
#pragma unroll
    for (int i = 0; i < 4; i++)
#pragma unroll
        for (int j = 0; j < 4; j++) acc[i][j] = (f32x4){0.f, 0.f, 0.f, 0.f};

    const size_t krow = (size_t)K * 2;
    const u16* Ab = A + (size_t)m0 * K;
    const u16* Bb = B + (size_t)n0 * K;
    char* smA = smem;
    char* smB = smem + 49152;

    auto stage_all = [&](int b, int k0) {
        size_t kb0 = (size_t)k0 * 2;
        stage_tile<256, 512>(Ab, krow, kb0, smA + b * 16384, t);
        stage_tile<128, 512>(Bb, krow, kb0, smB + b * 8192, t);
    };

    const int NU = K / BK;
    stage_all(0, 0);
    stage_all(1, BK);

    int cur = 0, pre = 2;
    for (int u = 0; u < NU; ++u) {
        if (u + 2 < NU) stage_all(pre, (u + 2) * BK);
        if (u + 2 < NU) vm_wait<2 * LPS>();
        else if (u + 1 < NU) vm_wait<LPS>();
        else vm_wait<0>();
        __builtin_amdgcn_s_barrier();

        const char* Ac = smA + cur * 16384;
        const char* Bc = smB + cur * 8192;
        bf16x8 fa[4], fb[4];
#pragma unroll
        for (int i = 0; i < 4; i++)
            fa[i] = *reinterpret_cast<const bf16x8*>(Ac + swz((wr * 64 + i * 16 + ro) * 64 + ko));
#pragma unroll
        for (int j = 0; j < 4; j++)
            fb[j] = *reinterpret_cast<const bf16x8*>(Bc + swz((wc * 64 + j * 16 + ro) * 64 + ko));
#pragma unroll
        for (int i = 0; i < 4; i++)
#pragma unroll
            for (int j = 0; j < 4; j++)
                acc[i][j] = __builtin_amdgcn_mfma_f32_16x16x32_bf16(fa[i], fb[j],
                                                                    acc[i][j], 0, 0, 0);
        __builtin_amdgcn_s_barrier();
        cur = (cur == 2) ? 0 : cur + 1;
        pre = (pre == 2) ? 0 : pre + 1;
    }

#pragma unroll
    for (int i = 0; i < 4; i++)
#pragma unroll
        for (int j = 0; j < 4; j++) {
            int col = n0 + wc * 64 + j * 16 + ro;
            int rbase = m0 + wr * 64 + i * 16 + (lane >> 4) * 4;
#pragma unroll
            for (int r = 0; r < 4; r++) {
                float v = acc[i][j][r];
                float s = v / (1.f + __expf(-v));
                act[(size_t)(rbase + r) * N + col] = f2bf(s);
            }
        }
}

// ---- sim body: 64x128 tile, 8 waves (2x4), 2-phase, SPLIT hi/lo ----
__device__ void sim_body(char* smem, int bx, int by,
                         const u16* __restrict__ Ahi, const u16* __restrict__ Alo,
                         const u16* __restrict__ Bhi, const u16* __restrict__ Blo,
                         float* __restrict__ C, int M, int N, int K) {
    const int t = threadIdx.x;
    const int lane = t & 63;
    const int wave = t >> 6;
    const int wr = wave >> 2, wc = wave & 3;   // 2x4 waves, WM=WN=32
    const int ro = lane & 15;
    const int ko = (lane >> 4) * 16;
    const int m0 = by * 64, n0 = bx * 128;

    f32x4 acc[2][2];
#pragma unroll
    for (int i = 0; i < 2; i++)
#pragma unroll
        for (int j = 0; j < 2; j++) acc[i][j] = (f32x4){0.f, 0.f, 0.f, 0.f};

    const size_t krow = (size_t)K * 2;
    const u16* Ahb = Ahi + (size_t)m0 * K;
    const u16* Alb = Alo + (size_t)m0 * K;
    const u16* Bhb = Bhi + (size_t)n0 * K;
    const u16* Blb = Blo + (size_t)n0 * K;
    char* smA = smem;
    char* smB = smem + 16384;

    auto stage_all = [&](int b, int k0) {
        size_t kb0 = (size_t)k0 * 2;
        {
            int sel = t >> 8, tt = t & 255;
            const u16* g = sel ? Alb : Ahb;
            int o = tt * 16;
            int os = swz(o);
            gload16((const char*)g + (size_t)(o >> 6) * krow + kb0 + (os & 63),
                    smA + b * 8192 + sel * 4096 + o);
        }
        {
            int o = t * 16, os = swz(o);
            gload16((const char*)Bhb + (size_t)(o >> 6) * krow + kb0 + (os & 63),
                    smB + b * 16384 + o);
        }
        {
            int o = t * 16, os = swz(o);
            gload16((const char*)Blb + (size_t)(o >> 6) * krow + kb0 + (os & 63),
                    smB + b * 16384 + 8192 + o);
        }
    };

    stage_all(0, 0);
    __syncthreads();
    int cur = 0;

    for (int k0 = 0; k0 < K; k0 += BK) {
        if (k0 + BK < K) stage_all(cur ^ 1, k0 + BK);
        const char* Ac = smA + cur * 8192;
        const char* Bc = smB + cur * 16384;
        bf16x8 fa[2], fal[2], fb[2], fbl[2];
#pragma unroll
        for (int i = 0; i < 2; i++) {
            int a = swz((wr * 32 + i * 16 + ro) * 64 + ko);
            fa[i] = *reinterpret_cast<const bf16x8*>(Ac + a);
            fal[i] = *reinterpret_cast<const bf16x8*>(Ac + 4096 + a);
        }
#pragma unroll
        for (int j = 0; j < 2; j++) {
            int a = swz((wc * 32 + j * 16 + ro) * 64 + ko);
            fb[j] = *reinterpret_cast<const bf16x8*>(Bc + a);
            fbl[j] = *reinterpret_cast<const bf16x8*>(Bc + 8192 + a);
        }
#pragma unroll
        for (int i = 0; i < 2; i++)
#pragma unroll
            for (int j = 0; j < 2; j++) {
                acc[i][j] = __builtin_amdgcn_mfma_f32_16x16x32_bf16(fa[i], fb[j],
                                                                    acc[i][j], 0, 0, 0);
                acc[i][j] = __builtin_amdgcn_mfma_f32_16x16x32_bf16(fa[i], fbl[j],
                                                                    acc[i][j], 0, 0, 0);
                acc[i][j] = __builtin_amdgcn_mfma_f32_16x16x32_bf16(fal[i], fb[j],
                                                                    acc[i][j], 0, 0, 0);
            }
        __syncthreads();
        cur ^= 1;
    }

#pragma unroll
    for (int i = 0; i < 2; i++)
#pragma unroll
        for (int j = 0; j < 2; j++) {
            int col = n0 + wc * 32 + j * 16 + ro;
            int rbase = m0 + wr * 32 + i * 16 + (lane >> 4) * 4;
#pragma unroll
            for (int r = 0; r < 4; r++)
                C[(size_t)(rbase + r) * N + col] = acc[i][j][r];
        }
}

// Fused: blocks [0,512) = up-proj (XCD-swizzled), [512,768) = sim projection.
__global__ __launch_bounds__(512, 4) void up_sim(
    const u16* __restrict__ hid_hi, const u16* __restrict__ hid_lo,
    const u16* __restrict__ wup,
    const u16* __restrict__ weff_hi, const u16* __restrict__ weff_lo,
    u16* __restrict__ act, float* __restrict__ Simb) {
    __shared__ char smem[73728];
    int bid = blockIdx.x;
    if (bid < 512) {
        int b2 = (bid & 7) * 64 + (bid >> 3);   // bijective XCD remap over 512
        up_body(smem, b2 % 32, b2 / 32, hid_hi, wup, act, TOKENS, IDIM, HDIM);
    } else {
        int sb = bid - 512;                      // grid 4 x 64
        sim_body(smem, sb & 3, sb >> 2, hid_hi, hid_lo, weff_hi, weff_lo, Simb,
                 TOKENS, QDIM, HDIM);
    }
}

// ---- 3-ring counted-vmcnt GEMM for the down projection ----
// z==0 writes v + ext (expst); z==1 writes v to Cout2 (added in reduce_add).
template <int TBM, int TBN, int WVM, int WVN, int KCHUNKS>
__global__ __launch_bounds__(WVM * WVN * 64) void gemm_p3(
    const u16* __restrict__ A, const u16* __restrict__ B,
    float* __restrict__ Cout, float* __restrict__ Cout2,
    const float* __restrict__ ext, int M, int N, int K) {
    constexpr int THREADS = WVM * WVN * 64;
    constexpr int WM = TBM / WVM, WN = TBN / WVN;
    constexpr int FM = WM / 16, FN = WN / 16;
    constexpr int LPS = (TBM + TBN) * 64 / (THREADS * 16);
    __shared__ u16 As[3][TBM * BK];
    __shared__ u16 Bs[3][TBN * BK];
    const int t = threadIdx.x;
    const int lane = t & 63;
    const int wave = t >> 6;
    const int wr = wave / WVN, wc = wave % WVN;
    const int ro = lane & 15;
    const int ko = (lane >> 4) * 16;

    int bx = blockIdx.x, by = blockIdx.y;
    {
        int gx = gridDim.x;
        int n = gx * gridDim.y;      // divisible by 8
        int bid = by * gx + bx;
        int q = n >> 3;
        bid = (bid & 7) * q + (bid >> 3);
        bx = bid % gx; by = bid / gx;
    }
    const int m0 = by * TBM;
    const int n0 = bx * TBN;
    const int klen = K / KCHUNKS;
    const int z = (KCHUNKS > 1) ? blockIdx.z : 0;
    const int koff = z * klen;
    const int NU = klen / BK;

    f32x4 acc[FM][FN];
#pragma unroll
    for (int i = 0; i < FM; i++)
#pragma unroll
        for (int j = 0; j < FN; j++) acc[i][j] = (f32x4){0.f, 0.f, 0.f, 0.f};

    const size_t krow = (size_t)K * 2;
    const u16* Ab = A + (size_t)m0 * K;
    const u16* Bb = B + (size_t)n0 * K;

    auto stage_all = [&](int b, int k0) {
        size_t kb0 = (size_t)k0 * 2;
        stage_tile<TBM, THREADS>(Ab, krow, kb0, (char*)As[b], t);
        stage_tile<TBN, THREADS>(Bb, krow, kb0, (char*)Bs[b], t);
    };

    stage_all(0, koff);
    stage_all(1, koff + BK);

    int cur = 0, pre = 2;
    for (int u = 0; u < NU; ++u) {
        int k0 = koff + u * BK;
        if (u + 2 < NU) stage_all(pre, k0 + 2 * BK);
        if (u + 2 < NU) vm_wait<2 * LPS>();
        else if (u + 1 < NU) vm_wait<LPS>();
        else vm_wait<0>();
        __builtin_amdgcn_s_barrier();

        const u16* Ac = As[cur];
        const u16* Bc = Bs[cur];
        bf16x8 fa[FM], fb[FN];
#pragma unroll
        for (int i = 0; i < FM; i++)
            fa[i] = *reinterpret_cast<const bf16x8*>(
                (const char*)Ac + swz((wr * WM + i * 16 + ro) * 64 + ko));
#pragma unroll
        for (int j = 0; j < FN; j++)
            fb[j] = *reinterpret_cast<const bf16x8*>(
                (const char*)Bc + swz((wc * WN + j * 16 + ro) * 64 + ko));
#pragma unroll
        for (int i = 0; i < FM; i++)
#pragma unroll
            for (int j = 0; j < FN; j++)
                acc[i][j] = __builtin_amdgcn_mfma_f32_16x16x32_bf16(fa[i], fb[j],
                                                                    acc[i][j], 0, 0, 0);
        __builtin_amdgcn_s_barrier();
        cur = (cur == 2) ? 0 : cur + 1;
        pre = (pre == 2) ? 0 : pre + 1;
    }

#pragma unroll
    for (int i = 0; i < FM; i++)
#pragma unroll
        for (int j = 0; j < FN; j++) {
            int col = n0 + wc * WN + j * 16 + ro;
            int rbase = m0 + wr * WM + i * 16 + (lane >> 4) * 4;
#pragma unroll
            for (int r = 0; r < 4; r++) {
                float v = acc[i][j][r];
                size_t off = (size_t)(rbase + r) * N + col;
                if (z == 0) Cout[off] = v + ext[off];
                else Cout2[off] = v;
            }
        }
}

// Rank of value v (lane l) among 64 values in LDS, JAX top_k tie order.
__device__ __forceinline__ int rank64(const float* base, float v, int l) {
    const float4* gv = reinterpret_cast<const float4*>(base);
    int rank = 0;
#pragma unroll
    for (int n = 0; n < 16; n++) {
        float4 o = gv[n];
        int b = n * 4;
        rank += (o.x > v) || (o.x == v && (b + 0) < l);
        rank += (o.y > v) || (o.y == v && (b + 1) < l);
        rank += (o.z > v) || (o.z == v && (b + 2) < l);
        rank += (o.w > v) || (o.w == v && (b + 3) < l);
    }
    return rank;
}

// Fused router + expert gather: one token per 512-thread block,
// fp8 decode via packed cvt_pk_f32_fp8 (2 elems/instr).
__global__ __launch_bounds__(512) void router_gather(
    const float* __restrict__ Simb, const u16* __restrict__ hid_bf,
    const u32* __restrict__ de_f8, const u32* __restrict__ ue_f8,
    float* __restrict__ expst) {
    __shared__ float sims[QDIM];
    __shared__ float topv[8][TOPK];
    __shared__ int topi[8][TOPK];
    __shared__ float pv[NHEADS][64];
    __shared__ float st8[NHEADS][TOPK];
    __shared__ int sid8[NHEADS][TOPK];
    __shared__ float gate8[NHEADS][TOPK];
    __shared__ float wks[NHEADS][TOPK];
    __shared__ float red[8][256];

    const int tok = blockIdx.x;
    const int tid = threadIdx.x;
    const int w = tid >> 6, l = tid & 63;

    sims[tid] = Simb[(size_t)tok * QDIM + tid];
    __syncthreads();

    {   // per-group rank
        float v = sims[w * 64 + l];
        int rank = rank64(sims + w * 64, v, l);
        if (rank < TOPK) { topv[w][rank] = v; topi[w][rank] = l; }
    }
    __syncthreads();

    if (w < NHEADS) pv[w][l] = topv[w][l >> 3] + topv[4 + w][l & 7];
    __syncthreads();

    if (w < NHEADS) {
        float v = pv[w][l];
        int rank = rank64(pv[w], v, l);
        if (rank < TOPK) {
            st8[w][rank] = v;
            sid8[w][rank] = topi[w][l >> 3] * NKEYS + topi[4 + w][l & 7];
        }
    }
    __syncthreads();

    if (tid < NHEADS * TOPK) {
        int h = tid >> 3, r = tid & 7;
        float m0 = st8[h][0];
        float s = 0.f;
#pragma unroll
        for (int i = 0; i < TOPK; i++) s += __expf(st8[h][i] - m0);
        gate8[h][r] = __expf(st8[h][r] - m0) / s;
    }
    __syncthreads();

    {   // dot phase: wave w -> head w>>1, experts kq..kq+3
        const int head = w >> 1, kq = (w & 1) * 4;
        u16x8 hv[2];
        const u16* hrow = hid_bf + (size_t)tok * HDIM + l * 16;
        hv[0] = *reinterpret_cast<const u16x8*>(hrow);
        hv[1] = *reinterpret_cast<const u16x8*>(hrow + 8);
        float h16[16];
#pragma unroll
        for (int t2 = 0; t2 < 8; t2++) {
            h16[t2] = bf2f(hv[0][t2]);
            h16[8 + t2] = bf2f(hv[1][t2]);
        }
        int eid[4];
        float gt[4];
#pragma unroll
        for (int j = 0; j < 4; j++) {
            eid[j] = sid8[head][kq + j];
            gt[j] = gate8[head][kq + j];
        }
        u32x4 dv[4];
#pragma unroll
        for (int j = 0; j < 4; j++)
            dv[j] = *reinterpret_cast<const u32x4*>(de_f8 + (size_t)eid[j] * 256 + l * 4);
        float dot[4];
#pragma unroll
        for (int j = 0; j < 4; j++) {
            float s = 0.f;
#pragma unroll
            for (int w2 = 0; w2 < 4; w2++) {
                u32 word = dv[j][w2];
                f32x2 lo = __builtin_amdgcn_cvt_pk_f32_fp8(word, false);
                f32x2 hi = __builtin_amdgcn_cvt_pk_f32_fp8(word, true);
                s += h16[w2 * 4 + 0] * lo[0] + h16[w2 * 4 + 1] * lo[1] +
                     h16[w2 * 4 + 2] * hi[0] + h16[w2 * 4 + 3] * hi[1];
            }
            dot[j] = s;
        }
#pragma unroll
        for (int m = 32; m; m >>= 1)
#pragma unroll
            for (int j = 0; j < 4; j++) dot[j] += __shfl_xor(dot[j], m, 64);
        if (l < 4) {
            float x = dot[l] * gt[l];
            wks[head][kq + l] = x / (1.f + __expf(-x));
        }
    }
    __syncthreads();

    {   // acc phase: wave w -> quarter q=w>>1, expert half hf=w&1
        const int q = w >> 1, hf = w & 1;
        float acc0 = 0.f, acc1 = 0.f, acc2 = 0.f, acc3 = 0.f;
        const u32* ubase = ue_f8 + q * 64 + l;
#pragma unroll
        for (int m = 0; m < 16; m++) {
            int mm = hf * 16 + m;
            int h = mm >> 3, k = mm & 7;
            int e = sid8[h][k];
            float wk = wks[h][k];
            u32 u = ubase[(size_t)e * 256];
            f32x2 lo = __builtin_amdgcn_cvt_pk_f32_fp8(u, false);
            f32x2 hi = __builtin_amdgcn_cvt_pk_f32_fp8(u, true);
            acc0 += wk * lo[0]; acc1 += wk * lo[1];
            acc2 += wk * hi[0]; acc3 += wk * hi[1];
        }
        *reinterpret_cast<float4*>(&red[w][l * 4]) = make_float4(acc0, acc1, acc2, acc3);
    }
    __syncthreads();

    {   // final: out quarter q = red[2q] + red[2q+1]
        int d = tid * 2;
        int qq = d >> 8, dq = d & 255;
        float2 a = *reinterpret_cast<float2*>(&red[2 * qq][dq]);
        float2 b = *reinterpret_cast<float2*>(&red[2 * qq + 1][dq]);
        float2 o;
        o.x = a.x + b.x;
        o.y = a.y + b.y;
        *reinterpret_cast<float2*>(expst + (size_t)tok * HDIM + d) = o;
    }
}

extern "C" void kernel_launch(void* const* d_in, const int* in_sizes, int n_in,
                              void* d_out, int out_size, void* d_ws, size_t ws_size,
                              hipStream_t stream) {
    const float* hidden = (const float*)d_in[0];
    const float* W_up = (const float*)d_in[1];
    const float* W_down = (const float*)d_in[2];
    const float* W_q = (const float*)d_in[3];
    const float* keys = (const float*)d_in[4];
    const float* down_embed = (const float*)d_in[5];
    const float* up_embed = (const float*)d_in[6];
    float* out = (float*)d_out;

    char* ws = (char*)d_ws;
    size_t off = 0;
    auto alloc = [&](size_t bytes) {
        void* p = ws + off;
        off += (bytes + 255) & ~(size_t)255;
        return p;
    };
    u16* hid_hi = (u16*)alloc((size_t)TOKENS * HDIM * 2);
    // hid_lo + Simb (16.78 MB) are dead after router_gather; down K-chunk-1
    // partial overlays them.
    u16* hid_lo = (u16*)alloc((size_t)TOKENS * HDIM * 2);
    float* Simb = (float*)alloc((size_t)TOKENS * QDIM * 4);
    float* partial = (float*)hid_lo;
    u16* weff_hi = (u16*)alloc((size_t)QDIM * HDIM * 2);
    u16* weff_lo = (u16*)alloc((size_t)QDIM * HDIM * 2);
    u16* wup = (u16*)alloc((size_t)IDIM * HDIM * 2);
    u16* wdn = (u16*)alloc((size_t)HDIM * IDIM * 2);
    u16* act = (u16*)alloc((size_t)TOKENS * IDIM * 2);
    u32* de_f8 = (u32*)alloc((size_t)4096 * HDIM);
    u32* ue_f8 = (u32*)alloc((size_t)4096 * HDIM);
    float* expst = (float*)alloc((size_t)TOKENS * HDIM * 4);

    cvt_all<<<(CVT_TOT + 255) / 256, 256, 0, stream>>>(
        hidden, W_up, W_down, down_embed, up_embed,
        hid_hi, hid_lo, wup, wdn, de_f8, ue_f8);
    weff_kernel<<<64, 256, 0, stream>>>(keys, W_q, weff_hi, weff_lo);

    // fused up-proj (512 blocks) + sim projection (256 blocks)
    up_sim<<<768, 512, 0, stream>>>(hid_hi, hid_lo, wup, weff_hi, weff_lo, act, Simb);

    router_gather<<<TOKENS, 512, 0, stream>>>(Simb, hid_hi, de_f8, ue_f8, expst);

    // down proj: 128x128 tile, 3-ring counted-vmcnt, K-split x2, XCD-swz
    gemm_p3<128, 128, 2, 2, 2>
        <<<dim3(HDIM / 128, TOKENS / 128, 2), 256, 0, stream>>>(
        act, wdn, out, partial, expst, TOKENS, HDIM, IDIM);
    reduce_add<<<(TOKENS * HDIM / 4 + 255) / 256, 256, 0, stream>>>(out, partial,
                                                                    TOKENS * HDIM / 4);
}

// Round 19
// 197.788 us; speedup vs baseline: 1.0051x; 1.0051x over previous
//
#include <hip/hip_runtime.h>

typedef unsigned short u16;
typedef unsigned int u32;

#define TOKENS 4096   // B*T
#define HDIM 1024
#define IDIM 4096
#define NHEADS 4
#define NKEYS 64
#define TOPK 8
#define QDIM 512      // 2 * NHEADS * 64

typedef __bf16 bf16x8 __attribute__((ext_vector_type(8)));
typedef float  f32x4  __attribute__((ext_vector_type(4)));
typedef float  f32x2  __attribute__((ext_vector_type(2)));
typedef u16    u16x8  __attribute__((ext_vector_type(8)));
typedef u32    u32x4  __attribute__((ext_vector_type(4)));

__device__ __forceinline__ u16 f2bf(float f) {
    u32 u = __float_as_uint(f);
    u += 0x7fffu + ((u >> 16) & 1u);   // RNE
    return (u16)(u >> 16);
}
__device__ __forceinline__ float bf2f(u16 h) { return __uint_as_float(((u32)h) << 16); }

#define H_N4   1048576   // TOKENS*HDIM/4
#define WUP_N4 1048576
#define WDN_N4 1048576
#define DE_N4  1048576
#define UE_N4  1048576
#define CVT_TOT (H_N4 + WUP_N4 + WDN_N4 + DE_N4 + UE_N4)

__device__ __forceinline__ void cvt1(const float* in, u16* hi, u16* lo, int i) {
    float4 v = reinterpret_cast<const float4*>(in)[i];
    float vf[4] = {v.x, v.y, v.z, v.w};
    ushort4 h;
    u16 hh[4];
#pragma unroll
    for (int j = 0; j < 4; j++) hh[j] = f2bf(vf[j]);
    h.x = hh[0]; h.y = hh[1]; h.z = hh[2]; h.w = hh[3];
    reinterpret_cast<ushort4*>(hi)[i] = h;
    if (lo) {
        ushort4 l4;
        u16 ll[4];
#pragma unroll
        for (int j = 0; j < 4; j++) ll[j] = f2bf(vf[j] - bf2f(hh[j]));
        l4.x = ll[0]; l4.y = ll[1]; l4.z = ll[2]; l4.w = ll[3];
        reinterpret_cast<ushort4*>(lo)[i] = l4;
    }
}

__device__ __forceinline__ void cvt1_f8(const float* in, u32* out8, int i) {
    float4 v = reinterpret_cast<const float4*>(in)[i];
    u32 w = __builtin_amdgcn_cvt_pk_fp8_f32(v.x, v.y, 0u, false);
    w = __builtin_amdgcn_cvt_pk_fp8_f32(v.z, v.w, w, true);
    out8[i] = w;
}

// All 5 tensor conversions in one streaming launch.
__global__ __launch_bounds__(256) void cvt_all(
    const float* __restrict__ hidden, const float* __restrict__ W_up,
    const float* __restrict__ W_down, const float* __restrict__ de,
    const float* __restrict__ ue,
    u16* __restrict__ hid_hi, u16* __restrict__ hid_lo,
    u16* __restrict__ wup, u16* __restrict__ wdn,
    u32* __restrict__ de_f8, u32* __restrict__ ue_f8) {
    int i = blockIdx.x * 256 + threadIdx.x;
    if (i >= CVT_TOT) return;
    if (i < H_N4) { cvt1(hidden, hid_hi, hid_lo, i); return; }
    i -= H_N4;
    if (i < WUP_N4) { cvt1(W_up, wup, nullptr, i); return; }
    i -= WUP_N4;
    if (i < WDN_N4) { cvt1(W_down, wdn, nullptr, i); return; }
    i -= WDN_N4;
    if (i < DE_N4) { cvt1_f8(de, de_f8, i); return; }
    i -= DE_N4;
    cvt1_f8(ue, ue_f8, i);
}

// Weff[(p*4+h)*64+k][d] = sum_n keys[h][k][p][n] * Wq[p*256+h*64+n][d],
// fp32 accumulate, split hi/lo bf16 output. Own kernel (R12 lesson).
__global__ __launch_bounds__(256) void weff_kernel(
    const float* __restrict__ keys, const float* __restrict__ Wq,
    u16* __restrict__ weff_hi, u16* __restrict__ weff_lo) {
    __shared__ float kk[64][65];
    __shared__ float wq_s[64][128];

    const int g = blockIdx.x >> 3, ds = blockIdx.x & 7;
    const int p = g >> 2, h = g & 3;
    const int d0 = ds * 128;
    const int t = threadIdx.x;
    const int base = p * 256 + h * 64;

    {
        int k = t >> 2, part = t & 3;
        const float* krow = keys + (((size_t)(h * NKEYS + k) * 2 + p) * 64);
#pragma unroll
        for (int j = 0; j < 4; j++) {
            int n0 = part * 16 + j * 4;
            float4 v = *reinterpret_cast<const float4*>(krow + n0);
            kk[k][n0 + 0] = v.x; kk[k][n0 + 1] = v.y;
            kk[k][n0 + 2] = v.z; kk[k][n0 + 3] = v.w;
        }
    }
    {
        int n = t >> 2, dpart = t & 3;
        const float* wrow = Wq + (size_t)(base + n) * HDIM + d0;
#pragma unroll
        for (int j = 0; j < 8; j++) {
            int dd = dpart * 32 + j * 4;
            float4 v = *reinterpret_cast<const float4*>(wrow + dd);
            *reinterpret_cast<float4*>(&wq_s[n][dd]) = v;
        }
    }
    __syncthreads();

    const int k = t & 63, dq = t >> 6;
    float acc[32];
#pragma unroll
    for (int i = 0; i < 32; i++) acc[i] = 0.f;
    for (int n = 0; n < 64; n++) {
        float kv = kk[k][n];
        const float4* wrow = reinterpret_cast<const float4*>(&wq_s[n][dq * 32]);
#pragma unroll
        for (int j = 0; j < 8; j++) {
            float4 w4 = wrow[j];
            acc[j * 4 + 0] += kv * w4.x; acc[j * 4 + 1] += kv * w4.y;
            acc[j * 4 + 2] += kv * w4.z; acc[j * 4 + 3] += kv * w4.w;
        }
    }
    size_t ro = (size_t)(g * 64 + k) * HDIM + d0 + dq * 32;
#pragma unroll
    for (int j = 0; j < 8; j++) {
        ushort4 hh, ll;
        u16 hv[4], lv[4];
#pragma unroll
        for (int i = 0; i < 4; i++) {
            float a = acc[j * 4 + i];
            hv[i] = f2bf(a);
            lv[i] = f2bf(a - bf2f(hv[i]));
        }
        hh.x = hv[0]; hh.y = hv[1]; hh.z = hv[2]; hh.w = hv[3];
        ll.x = lv[0]; ll.y = lv[1]; ll.z = lv[2]; ll.w = lv[3];
        *reinterpret_cast<ushort4*>(weff_hi + ro + j * 4) = hh;
        *reinterpret_cast<ushort4*>(weff_lo + ro + j * 4) = ll;
    }
}

// out += partial
__global__ __launch_bounds__(256) void reduce_add(float* __restrict__ out,
                                                  const float* __restrict__ p, int n4) {
    int i = blockIdx.x * 256 + threadIdx.x;
    if (i >= n4) return;
    float4 a = reinterpret_cast<const float4*>(out)[i];
    float4 b = reinterpret_cast<const float4*>(p)[i];
    a.x += b.x; a.y += b.y; a.z += b.z; a.w += b.w;
    reinterpret_cast<float4*>(out)[i] = a;
}

__device__ __forceinline__ void gload16(const void* g, void* s) {
    auto gp = reinterpret_cast<const __attribute__((address_space(1))) u32*>(
        reinterpret_cast<uintptr_t>(g));
    auto sp = reinterpret_cast<__attribute__((address_space(3))) u32*>(
        reinterpret_cast<uintptr_t>(s));
    __builtin_amdgcn_global_load_lds(gp, sp, 16, 0, 0);
}

#define BK 32

// LDS rows of 64B; swizzle slot ^= (row>>1)&3 (verified: 0 bank conflicts).
__device__ __forceinline__ int swz(int a) { return a ^ (((a >> 7) & 3) << 4); }

template <int ROWS, int THREADS>
__device__ __forceinline__ void stage_tile(const u16* g, size_t krow_b, size_t kb0,
                                           char* s, int t) {
#pragma unroll
    for (int rnd = 0; rnd < ROWS * 64 / (THREADS * 16); rnd++) {
        int o = t * 16 + rnd * THREADS * 16;
        int os = swz(o);
        int row = o >> 6, kb = os & 63;
        gload16((const char*)g + (size_t)row * krow_b + kb0 + kb, s + o);
    }
}

template <int N>
__device__ __forceinline__ void vm_wait() {
    if constexpr (N == 0) asm volatile("s_waitcnt vmcnt(0)" ::: "memory");
    else if constexpr (N == 3) asm volatile("s_waitcnt vmcnt(3)" ::: "memory");
    else if constexpr (N == 4) asm volatile("s_waitcnt vmcnt(4)" ::: "memory");
    else if constexpr (N == 6) asm volatile("s_waitcnt vmcnt(6)" ::: "memory");
    else if constexpr (N == 8) asm volatile("s_waitcnt vmcnt(8)" ::: "memory");
    else static_assert(N == 0, "unsupported vmcnt");
}

// ---- up-proj body: 256x128 tile, 8 waves (4x2), 3-ring counted vmcnt ----
__device__ void up_body(char* smem, int bx, int by,
                        const u16* __restrict__ A, const u16* __restrict__ B,
                        u16* __restrict__ act, int M, int N, int K) {
    constexpr int LPS = 3;   // (256+128)*64 / (512*16)
    const int t = threadIdx.x;
    const int lane = t & 63;
    const int wave = t >> 6;
    const int wr = wave >> 1, wc = wave & 1;   // 4x2 waves, WM=WN=64
    const int ro = lane & 15;
    const int ko = (lane >> 4) * 16;
    const int m0 = by * 256, n0 = bx * 128;

    f32x4 acc[4][4];
#pragma unroll
    for (int i = 0; i < 4; i++)
#pragma unroll
        for (int j = 0; j < 4; j++) acc[i][j] = (f32x4){0.f, 0.f, 0.f, 0.f};

    const size_t krow = (size_t)K * 2;
    const u16* Ab = A + (size_t)m0 * K;
    const u16* Bb = B + (size_t)n0 * K;
    char* smA = smem;
    char* smB = smem + 49152;

    auto stage_all = [&](int b, int k0) {
        size_t kb0 = (size_t)k0 * 2;
        stage_tile<256, 512>(Ab, krow, kb0, smA + b * 16384, t);
        stage_tile<128, 512>(Bb, krow, kb0, smB + b * 8192, t);
    };

    const int NU = K / BK;
    stage_all(0, 0);
    stage_all(1, BK);

    int cur = 0, pre = 2;
    for (int u = 0; u < NU; ++u) {
        if (u + 2 < NU) stage_all(pre, (u + 2) * BK);
        if (u + 2 < NU) vm_wait<2 * LPS>();
        else if (u + 1 < NU) vm_wait<LPS>();
        else vm_wait<0>();
        __builtin_amdgcn_s_barrier();

        const char* Ac = smA + cur * 16384;
        const char* Bc = smB + cur * 8192;
        bf16x8 fa[4], fb[4];
#pragma unroll
        for (int i = 0; i < 4; i++)
            fa[i] = *reinterpret_cast<const bf16x8*>(Ac + swz((wr * 64 + i * 16 + ro) * 64 + ko));
#pragma unroll
        for (int j = 0; j < 4; j++)
            fb[j] = *reinterpret_cast<const bf16x8*>(Bc + swz((wc * 64 + j * 16 + ro) * 64 + ko));
#pragma unroll
        for (int i = 0; i < 4; i++)
#pragma unroll
            for (int j = 0; j < 4; j++)
                acc[i][j] = __builtin_amdgcn_mfma_f32_16x16x32_bf16(fa[i], fb[j],
                                                                    acc[i][j], 0, 0, 0);
        __builtin_amdgcn_s_barrier();
        cur = (cur == 2) ? 0 : cur + 1;
        pre = (pre == 2) ? 0 : pre + 1;
    }

#pragma unroll
    for (int i = 0; i < 4; i++)
#pragma unroll
        for (int j = 0; j < 4; j++) {
            int col = n0 + wc * 64 + j * 16 + ro;
            int rbase = m0 + wr * 64 + i * 16 + (lane >> 4) * 4;
#pragma unroll
            for (int r = 0; r < 4; r++) {
                float v = acc[i][j][r];
                float s = v / (1.f + __expf(-v));
                act[(size_t)(rbase + r) * N + col] = f2bf(s);
            }
        }
}

// ---- sim body: 64x128 tile, 8 waves (2x4), 2-phase, SPLIT hi/lo ----
__device__ void sim_body(char* smem, int bx, int by,
                         const u16* __restrict__ Ahi, const u16* __restrict__ Alo,
                         const u16* __restrict__ Bhi, const u16* __restrict__ Blo,
                         float* __restrict__ C, int M, int N, int K) {
    const int t = threadIdx.x;
    const int lane = t & 63;
    const int wave = t >> 6;
    const int wr = wave >> 2, wc = wave & 3;   // 2x4 waves, WM=WN=32
    const int ro = lane & 15;
    const int ko = (lane >> 4) * 16;
    const int m0 = by * 64, n0 = bx * 128;

    f32x4 acc[2][2];
#pragma unroll
    for (int i = 0; i < 2; i++)
#pragma unroll
        for (int j = 0; j < 2; j++) acc[i][j] = (f32x4){0.f, 0.f, 0.f, 0.f};

    const size_t krow = (size_t)K * 2;
    const u16* Ahb = Ahi + (size_t)m0 * K;
    const u16* Alb = Alo + (size_t)m0 * K;
    const u16* Bhb = Bhi + (size_t)n0 * K;
    const u16* Blb = Blo + (size_t)n0 * K;
    char* smA = smem;
    char* smB = smem + 16384;

    auto stage_all = [&](int b, int k0) {
        size_t kb0 = (size_t)k0 * 2;
        {
            int sel = t >> 8, tt = t & 255;
            const u16* g = sel ? Alb : Ahb;
            int o = tt * 16;
            int os = swz(o);
            gload16((const char*)g + (size_t)(o >> 6) * krow + kb0 + (os & 63),
                    smA + b * 8192 + sel * 4096 + o);
        }
        {
            int o = t * 16, os = swz(o);
            gload16((const char*)Bhb + (size_t)(o >> 6) * krow + kb0 + (os & 63),
                    smB + b * 16384 + o);
        }
        {
            int o = t * 16, os = swz(o);
            gload16((const char*)Blb + (size_t)(o >> 6) * krow + kb0 + (os & 63),
                    smB + b * 16384 + 8192 + o);
        }
    };

    stage_all(0, 0);
    __syncthreads();
    int cur = 0;

    for (int k0 = 0; k0 < K; k0 += BK) {
        if (k0 + BK < K) stage_all(cur ^ 1, k0 + BK);
        const char* Ac = smA + cur * 8192;
        const char* Bc = smB + cur * 16384;
        bf16x8 fa[2], fal[2], fb[2], fbl[2];
#pragma unroll
        for (int i = 0; i < 2; i++) {
            int a = swz((wr * 32 + i * 16 + ro) * 64 + ko);
            fa[i] = *reinterpret_cast<const bf16x8*>(Ac + a);
            fal[i] = *reinterpret_cast<const bf16x8*>(Ac + 4096 + a);
        }
#pragma unroll
        for (int j = 0; j < 2; j++) {
            int a = swz((wc * 32 + j * 16 + ro) * 64 + ko);
            fb[j] = *reinterpret_cast<const bf16x8*>(Bc + a);
            fbl[j] = *reinterpret_cast<const bf16x8*>(Bc + 8192 + a);
        }
#pragma unroll
        for (int i = 0; i < 2; i++)
#pragma unroll
            for (int j = 0; j < 2; j++) {
                acc[i][j] = __builtin_amdgcn_mfma_f32_16x16x32_bf16(fa[i], fb[j],
                                                                    acc[i][j], 0, 0, 0);
                acc[i][j] = __builtin_amdgcn_mfma_f32_16x16x32_bf16(fa[i], fbl[j],
                                                                    acc[i][j], 0, 0, 0);
                acc[i][j] = __builtin_amdgcn_mfma_f32_16x16x32_bf16(fal[i], fb[j],
                                                                    acc[i][j], 0, 0, 0);
            }
        __syncthreads();
        cur ^= 1;
    }

#pragma unroll
    for (int i = 0; i < 2; i++)
#pragma unroll
        for (int j = 0; j < 2; j++) {
            int col = n0 + wc * 32 + j * 16 + ro;
            int rbase = m0 + wr * 32 + i * 16 + (lane >> 4) * 4;
#pragma unroll
            for (int r = 0; r < 4; r++)
                C[(size_t)(rbase + r) * N + col] = acc[i][j][r];
        }
}

// Fused: blocks [0,256) = SIM (dispatched FIRST: sim blocks co-reside with
// the first up blocks and retire early -> up backfills = overlap, not tail;
// R14/R15 dispatch-order evidence), blocks [256,768) = up-proj
// (XCD-swizzled on ub = bid-256; 256%8==0 keeps the XCD phase).
__global__ __launch_bounds__(512, 4) void up_sim(
    const u16* __restrict__ hid_hi, const u16* __restrict__ hid_lo,
    const u16* __restrict__ wup,
    const u16* __restrict__ weff_hi, const u16* __restrict__ weff_lo,
    u16* __restrict__ act, float* __restrict__ Simb) {
    __shared__ char smem[73728];
    int bid = blockIdx.x;
    if (bid < 256) {
        int sb = bid;                            // grid 4 x 64
        sim_body(smem, sb & 3, sb >> 2, hid_hi, hid_lo, weff_hi, weff_lo, Simb,
                 TOKENS, QDIM, HDIM);
    } else {
        int ub = bid - 256;
        int b2 = (ub & 7) * 64 + (ub >> 3);      // bijective XCD remap over 512
        up_body(smem, b2 % 32, b2 / 32, hid_hi, wup, act, TOKENS, IDIM, HDIM);
    }
}

// ---- 3-ring counted-vmcnt GEMM for the down projection ----
// z==0 writes v + ext (expst); z==1 writes v to Cout2 (added in reduce_add).
template <int TBM, int TBN, int WVM, int WVN, int KCHUNKS>
__global__ __launch_bounds__(WVM * WVN * 64) void gemm_p3(
    const u16* __restrict__ A, const u16* __restrict__ B,
    float* __restrict__ Cout, float* __restrict__ Cout2,
    const float* __restrict__ ext, int M, int N, int K) {
    constexpr int THREADS = WVM * WVN * 64;
    constexpr int WM = TBM / WVM, WN = TBN / WVN;
    constexpr int FM = WM / 16, FN = WN / 16;
    constexpr int LPS = (TBM + TBN) * 64 / (THREADS * 16);
    __shared__ u16 As[3][TBM * BK];
    __shared__ u16 Bs[3][TBN * BK];
    const int t = threadIdx.x;
    const int lane = t & 63;
    const int wave = t >> 6;
    const int wr = wave / WVN, wc = wave % WVN;
    const int ro = lane & 15;
    const int ko = (lane >> 4) * 16;

    int bx = blockIdx.x, by = blockIdx.y;
    {
        int gx = gridDim.x;
        int n = gx * gridDim.y;      // divisible by 8
        int bid = by * gx + bx;
        int q = n >> 3;
        bid = (bid & 7) * q + (bid >> 3);
        bx = bid % gx; by = bid / gx;
    }
    const int m0 = by * TBM;
    const int n0 = bx * TBN;
    const int klen = K / KCHUNKS;
    const int z = (KCHUNKS > 1) ? blockIdx.z : 0;
    const int koff = z * klen;
    const int NU = klen / BK;

    f32x4 acc[FM][FN];
#pragma unroll
    for (int i = 0; i < FM; i++)
#pragma unroll
        for (int j = 0; j < FN; j++) acc[i][j] = (f32x4){0.f, 0.f, 0.f, 0.f};

    const size_t krow = (size_t)K * 2;
    const u16* Ab = A + (size_t)m0 * K;
    const u16* Bb = B + (size_t)n0 * K;

    auto stage_all = [&](int b, int k0) {
        size_t kb0 = (size_t)k0 * 2;
        stage_tile<TBM, THREADS>(Ab, krow, kb0, (char*)As[b], t);
        stage_tile<TBN, THREADS>(Bb, krow, kb0, (char*)Bs[b], t);
    };

    stage_all(0, koff);
    stage_all(1, koff + BK);

    int cur = 0, pre = 2;
    for (int u = 0; u < NU; ++u) {
        int k0 = koff + u * BK;
        if (u + 2 < NU) stage_all(pre, k0 + 2 * BK);
        if (u + 2 < NU) vm_wait<2 * LPS>();
        else if (u + 1 < NU) vm_wait<LPS>();
        else vm_wait<0>();
        __builtin_amdgcn_s_barrier();

        const u16* Ac = As[cur];
        const u16* Bc = Bs[cur];
        bf16x8 fa[FM], fb[FN];
#pragma unroll
        for (int i = 0; i < FM; i++)
            fa[i] = *reinterpret_cast<const bf16x8*>(
                (const char*)Ac + swz((wr * WM + i * 16 + ro) * 64 + ko));
#pragma unroll
        for (int j = 0; j < FN; j++)
            fb[j] = *reinterpret_cast<const bf16x8*>(
                (const char*)Bc + swz((wc * WN + j * 16 + ro) * 64 + ko));
#pragma unroll
        for (int i = 0; i < FM; i++)
#pragma unroll
            for (int j = 0; j < FN; j++)
                acc[i][j] = __builtin_amdgcn_mfma_f32_16x16x32_bf16(fa[i], fb[j],
                                                                    acc[i][j], 0, 0, 0);
        __builtin_amdgcn_s_barrier();
        cur = (cur == 2) ? 0 : cur + 1;
        pre = (pre == 2) ? 0 : pre + 1;
    }

#pragma unroll
    for (int i = 0; i < FM; i++)
#pragma unroll
        for (int j = 0; j < FN; j++) {
            int col = n0 + wc * WN + j * 16 + ro;
            int rbase = m0 + wr * WM + i * 16 + (lane >> 4) * 4;
#pragma unroll
            for (int r = 0; r < 4; r++) {
                float v = acc[i][j][r];
                size_t off = (size_t)(rbase + r) * N + col;
                if (z == 0) Cout[off] = v + ext[off];
                else Cout2[off] = v;
            }
        }
}

// Rank of value v (lane l) among 64 values in LDS, JAX top_k tie order.
__device__ __forceinline__ int rank64(const float* base, float v, int l) {
    const float4* gv = reinterpret_cast<const float4*>(base);
    int rank = 0;
#pragma unroll
    for (int n = 0; n < 16; n++) {
        float4 o = gv[n];
        int b = n * 4;
        rank += (o.x > v) || (o.x == v && (b + 0) < l);
        rank += (o.y > v) || (o.y == v && (b + 1) < l);
        rank += (o.z > v) || (o.z == v && (b + 2) < l);
        rank += (o.w > v) || (o.w == v && (b + 3) < l);
    }
    return rank;
}

// Fused router + expert gather: one token per 512-thread block,
// fp8 decode via packed cvt_pk_f32_fp8 (2 elems/instr).
__global__ __launch_bounds__(512) void router_gather(
    const float* __restrict__ Simb, const u16* __restrict__ hid_bf,
    const u32* __restrict__ de_f8, const u32* __restrict__ ue_f8,
    float* __restrict__ expst) {
    __shared__ float sims[QDIM];
    __shared__ float topv[8][TOPK];
    __shared__ int topi[8][TOPK];
    __shared__ float pv[NHEADS][64];
    __shared__ float st8[NHEADS][TOPK];
    __shared__ int sid8[NHEADS][TOPK];
    __shared__ float gate8[NHEADS][TOPK];
    __shared__ float wks[NHEADS][TOPK];
    __shared__ float red[8][256];

    const int tok = blockIdx.x;
    const int tid = threadIdx.x;
    const int w = tid >> 6, l = tid & 63;

    sims[tid] = Simb[(size_t)tok * QDIM + tid];
    __syncthreads();

    {   // per-group rank
        float v = sims[w * 64 + l];
        int rank = rank64(sims + w * 64, v, l);
        if (rank < TOPK) { topv[w][rank] = v; topi[w][rank] = l; }
    }
    __syncthreads();

    if (w < NHEADS) pv[w][l] = topv[w][l >> 3] + topv[4 + w][l & 7];
    __syncthreads();

    if (w < NHEADS) {
        float v = pv[w][l];
        int rank = rank64(pv[w], v, l);
        if (rank < TOPK) {
            st8[w][rank] = v;
            sid8[w][rank] = topi[w][l >> 3] * NKEYS + topi[4 + w][l & 7];
        }
    }
    __syncthreads();

    if (tid < NHEADS * TOPK) {
        int h = tid >> 3, r = tid & 7;
        float m0 = st8[h][0];
        float s = 0.f;
#pragma unroll
        for (int i = 0; i < TOPK; i++) s += __expf(st8[h][i] - m0);
        gate8[h][r] = __expf(st8[h][r] - m0) / s;
    }
    __syncthreads();

    {   // dot phase: wave w -> head w>>1, experts kq..kq+3
        const int head = w >> 1, kq = (w & 1) * 4;
        u16x8 hv[2];
        const u16* hrow = hid_bf + (size_t)tok * HDIM + l * 16;
        hv[0] = *reinterpret_cast<const u16x8*>(hrow);
        hv[1] = *reinterpret_cast<const u16x8*>(hrow + 8);
        float h16[16];
#pragma unroll
        for (int t2 = 0; t2 < 8; t2++) {
            h16[t2] = bf2f(hv[0][t2]);
            h16[8 + t2] = bf2f(hv[1][t2]);
        }
        int eid[4];
        float gt[4];
#pragma unroll
        for (int j = 0; j < 4; j++) {
            eid[j] = sid8[head][kq + j];
            gt[j] = gate8[head][kq + j];
        }
        u32x4 dv[4];
#pragma unroll
        for (int j = 0; j < 4; j++)
            dv[j] = *reinterpret_cast<const u32x4*>(de_f8 + (size_t)eid[j] * 256 + l * 4);
        float dot[4];
#pragma unroll
        for (int j = 0; j < 4; j++) {
            float s = 0.f;
#pragma unroll
            for (int w2 = 0; w2 < 4; w2++) {
                u32 word = dv[j][w2];
                f32x2 lo = __builtin_amdgcn_cvt_pk_f32_fp8(word, false);
                f32x2 hi = __builtin_amdgcn_cvt_pk_f32_fp8(word, true);
                s += h16[w2 * 4 + 0] * lo[0] + h16[w2 * 4 + 1] * lo[1] +
                     h16[w2 * 4 + 2] * hi[0] + h16[w2 * 4 + 3] * hi[1];
            }
            dot[j] = s;
        }
#pragma unroll
        for (int m = 32; m; m >>= 1)
#pragma unroll
            for (int j = 0; j < 4; j++) dot[j] += __shfl_xor(dot[j], m, 64);
        if (l < 4) {
            float x = dot[l] * gt[l];
            wks[head][kq + l] = x / (1.f + __expf(-x));
        }
    }
    __syncthreads();

    {   // acc phase: wave w -> quarter q=w>>1, expert half hf=w&1
        const int q = w >> 1, hf = w & 1;
        float acc0 = 0.f, acc1 = 0.f, acc2 = 0.f, acc3 = 0.f;
        const u32* ubase = ue_f8 + q * 64 + l;
#pragma unroll
        for (int m = 0; m < 16; m++) {
            int mm = hf * 16 + m;
            int h = mm >> 3, k = mm & 7;
            int e = sid8[h][k];
            float wk = wks[h][k];
            u32 u = ubase[(size_t)e * 256];
            f32x2 lo = __builtin_amdgcn_cvt_pk_f32_fp8(u, false);
            f32x2 hi = __builtin_amdgcn_cvt_pk_f32_fp8(u, true);
            acc0 += wk * lo[0]; acc1 += wk * lo[1];
            acc2 += wk * hi[0]; acc3 += wk * hi[1];
        }
        *reinterpret_cast<float4*>(&red[w][l * 4]) = make_float4(acc0, acc1, acc2, acc3);
    }
    __syncthreads();

    {   // final: out quarter q = red[2q] + red[2q+1]
        int d = tid * 2;
        int qq = d >> 8, dq = d & 255;
        float2 a = *reinterpret_cast<float2*>(&red[2 * qq][dq]);
        float2 b = *reinterpret_cast<float2*>(&red[2 * qq + 1][dq]);
        float2 o;
        o.x = a.x + b.x;
        o.y = a.y + b.y;
        *reinterpret_cast<float2*>(expst + (size_t)tok * HDIM + d) = o;
    }
}

extern "C" void kernel_launch(void* const* d_in, const int* in_sizes, int n_in,
                              void* d_out, int out_size, void* d_ws, size_t ws_size,
                              hipStream_t stream) {
    const float* hidden = (const float*)d_in[0];
    const float* W_up = (const float*)d_in[1];
    const float* W_down = (const float*)d_in[2];
    const float* W_q = (const float*)d_in[3];
    const float* keys = (const float*)d_in[4];
    const float* down_embed = (const float*)d_in[5];
    const float* up_embed = (const float*)d_in[6];
    float* out = (float*)d_out;

    char* ws = (char*)d_ws;
    size_t off = 0;
    auto alloc = [&](size_t bytes) {
        void* p = ws + off;
        off += (bytes + 255) & ~(size_t)255;
        return p;
    };
    u16* hid_hi = (u16*)alloc((size_t)TOKENS * HDIM * 2);
    // hid_lo + Simb (16.78 MB) are dead after router_gather; down K-chunk-1
    // partial overlays them.
    u16* hid_lo = (u16*)alloc((size_t)TOKENS * HDIM * 2);
    float* Simb = (float*)alloc((size_t)TOKENS * QDIM * 4);
    float* partial = (float*)hid_lo;
    u16* weff_hi = (u16*)alloc((size_t)QDIM * HDIM * 2);
    u16* weff_lo = (u16*)alloc((size_t)QDIM * HDIM * 2);
    u16* wup = (u16*)alloc((size_t)IDIM * HDIM * 2);
    u16* wdn = (u16*)alloc((size_t)HDIM * IDIM * 2);
    u16* act = (u16*)alloc((size_t)TOKENS * IDIM * 2);
    u32* de_f8 = (u32*)alloc((size_t)4096 * HDIM);
    u32* ue_f8 = (u32*)alloc((size_t)4096 * HDIM);
    float* expst = (float*)alloc((size_t)TOKENS * HDIM * 4);

    cvt_all<<<(CVT_TOT + 255) / 256, 256, 0, stream>>>(
        hidden, W_up, W_down, down_embed, up_embed,
        hid_hi, hid_lo, wup, wdn, de_f8, ue_f8);
    weff_kernel<<<64, 256, 0, stream>>>(keys, W_q, weff_hi, weff_lo);

    // fused sim (256, first -> overlaps) + up-proj (512)
    up_sim<<<768, 512, 0, stream>>>(hid_hi, hid_lo, wup, weff_hi, weff_lo, act, Simb);

    router_gather<<<TOKENS, 512, 0, stream>>>(Simb, hid_hi, de_f8, ue_f8, expst);

    // down proj: 128x128 tile, 3-ring counted-vmcnt, K-split x2, XCD-swz
    gemm_p3<128, 128, 2, 2, 2>
        <<<dim3(HDIM / 128, TOKENS / 128, 2), 256, 0, stream>>>(
        act, wdn, out, partial, expst, TOKENS, HDIM, IDIM);
    reduce_add<<<(TOKENS * HDIM / 4 + 255) / 256, 256, 0, stream>>>(out, partial,
                                                                    TOKENS * HDIM / 4);
}

// Round 20
// 197.142 us; speedup vs baseline: 1.0084x; 1.0033x over previous
//
#include <hip/hip_runtime.h>

typedef unsigned short u16;
typedef unsigned int u32;

#define TOKENS 4096   // B*T
#define HDIM 1024
#define IDIM 4096
#define NHEADS 4
#define NKEYS 64
#define TOPK 8
#define QDIM 512      // 2 * NHEADS * 64

typedef __bf16 bf16x8 __attribute__((ext_vector_type(8)));
typedef float  f32x4  __attribute__((ext_vector_type(4)));
typedef float  f32x2  __attribute__((ext_vector_type(2)));
typedef u16    u16x8  __attribute__((ext_vector_type(8)));
typedef u32    u32x4  __attribute__((ext_vector_type(4)));

__device__ __forceinline__ u16 f2bf(float f) {
    u32 u = __float_as_uint(f);
    u += 0x7fffu + ((u >> 16) & 1u);   // RNE
    return (u16)(u >> 16);
}
__device__ __forceinline__ float bf2f(u16 h) { return __uint_as_float(((u32)h) << 16); }

#define H_N4   1048576   // TOKENS*HDIM/4
#define WUP_N4 1048576
#define WDN_N4 1048576
#define DE_N4  1048576
#define UE_N4  1048576
#define CVT_TOT (H_N4 + WUP_N4 + WDN_N4 + DE_N4 + UE_N4)

__device__ __forceinline__ void cvt1(const float* in, u16* hi, u16* lo, int i) {
    float4 v = reinterpret_cast<const float4*>(in)[i];
    float vf[4] = {v.x, v.y, v.z, v.w};
    ushort4 h;
    u16 hh[4];
#pragma unroll
    for (int j = 0; j < 4; j++) hh[j] = f2bf(vf[j]);
    h.x = hh[0]; h.y = hh[1]; h.z = hh[2]; h.w = hh[3];
    reinterpret_cast<ushort4*>(hi)[i] = h;
    if (lo) {
        ushort4 l4;
        u16 ll[4];
#pragma unroll
        for (int j = 0; j < 4; j++) ll[j] = f2bf(vf[j] - bf2f(hh[j]));
        l4.x = ll[0]; l4.y = ll[1]; l4.z = ll[2]; l4.w = ll[3];
        reinterpret_cast<ushort4*>(lo)[i] = l4;
    }
}

__device__ __forceinline__ void cvt1_f8(const float* in, u32* out8, int i) {
    float4 v = reinterpret_cast<const float4*>(in)[i];
    u32 w = __builtin_amdgcn_cvt_pk_fp8_f32(v.x, v.y, 0u, false);
    w = __builtin_amdgcn_cvt_pk_fp8_f32(v.z, v.w, w, true);
    out8[i] = w;
}

// All 5 tensor conversions in one streaming launch.
__global__ __launch_bounds__(256) void cvt_all(
    const float* __restrict__ hidden, const float* __restrict__ W_up,
    const float* __restrict__ W_down, const float* __restrict__ de,
    const float* __restrict__ ue,
    u16* __restrict__ hid_hi, u16* __restrict__ hid_lo,
    u16* __restrict__ wup, u16* __restrict__ wdn,
    u32* __restrict__ de_f8, u32* __restrict__ ue_f8) {
    int i = blockIdx.x * 256 + threadIdx.x;
    if (i >= CVT_TOT) return;
    if (i < H_N4) { cvt1(hidden, hid_hi, hid_lo, i); return; }
    i -= H_N4;
    if (i < WUP_N4) { cvt1(W_up, wup, nullptr, i); return; }
    i -= WUP_N4;
    if (i < WDN_N4) { cvt1(W_down, wdn, nullptr, i); return; }
    i -= WDN_N4;
    if (i < DE_N4) { cvt1_f8(de, de_f8, i); return; }
    i -= DE_N4;
    cvt1_f8(ue, ue_f8, i);
}

// Weff[(p*4+h)*64+k][d] = sum_n keys[h][k][p][n] * Wq[p*256+h*64+n][d],
// fp32 accumulate, split hi/lo bf16 output. Own kernel (R12 lesson).
__global__ __launch_bounds__(256) void weff_kernel(
    const float* __restrict__ keys, const float* __restrict__ Wq,
    u16* __restrict__ weff_hi, u16* __restrict__ weff_lo) {
    __shared__ float kk[64][65];
    __shared__ float wq_s[64][128];

    const int g = blockIdx.x >> 3, ds = blockIdx.x & 7;
    const int p = g >> 2, h = g & 3;
    const int d0 = ds * 128;
    const int t = threadIdx.x;
    const int base = p * 256 + h * 64;

    {
        int k = t >> 2, part = t & 3;
        const float* krow = keys + (((size_t)(h * NKEYS + k) * 2 + p) * 64);
#pragma unroll
        for (int j = 0; j < 4; j++) {
            int n0 = part * 16 + j * 4;
            float4 v = *reinterpret_cast<const float4*>(krow + n0);
            kk[k][n0 + 0] = v.x; kk[k][n0 + 1] = v.y;
            kk[k][n0 + 2] = v.z; kk[k][n0 + 3] = v.w;
        }
    }
    {
        int n = t >> 2, dpart = t & 3;
        const float* wrow = Wq + (size_t)(base + n) * HDIM + d0;
#pragma unroll
        for (int j = 0; j < 8; j++) {
            int dd = dpart * 32 + j * 4;
            float4 v = *reinterpret_cast<const float4*>(wrow + dd);
            *reinterpret_cast<float4*>(&wq_s[n][dd]) = v;
        }
    }
    __syncthreads();

    const int k = t & 63, dq = t >> 6;
    float acc[32];
#pragma unroll
    for (int i = 0; i < 32; i++) acc[i] = 0.f;
    for (int n = 0; n < 64; n++) {
        float kv = kk[k][n];
        const float4* wrow = reinterpret_cast<const float4*>(&wq_s[n][dq * 32]);
#pragma unroll
        for (int j = 0; j < 8; j++) {
            float4 w4 = wrow[j];
            acc[j * 4 + 0] += kv * w4.x; acc[j * 4 + 1] += kv * w4.y;
            acc[j * 4 + 2] += kv * w4.z; acc[j * 4 + 3] += kv * w4.w;
        }
    }
    size_t ro = (size_t)(g * 64 + k) * HDIM + d0 + dq * 32;
#pragma unroll
    for (int j = 0; j < 8; j++) {
        ushort4 hh, ll;
        u16 hv[4], lv[4];
#pragma unroll
        for (int i = 0; i < 4; i++) {
            float a = acc[j * 4 + i];
            hv[i] = f2bf(a);
            lv[i] = f2bf(a - bf2f(hv[i]));
        }
        hh.x = hv[0]; hh.y = hv[1]; hh.z = hv[2]; hh.w = hv[3];
        ll.x = lv[0]; ll.y = lv[1]; ll.z = lv[2]; ll.w = lv[3];
        *reinterpret_cast<ushort4*>(weff_hi + ro + j * 4) = hh;
        *reinterpret_cast<ushort4*>(weff_lo + ro + j * 4) = ll;
    }
}

// out += partial
__global__ __launch_bounds__(256) void reduce_add(float* __restrict__ out,
                                                  const float* __restrict__ p, int n4) {
    int i = blockIdx.x * 256 + threadIdx.x;
    if (i >= n4) return;
    float4 a = reinterpret_cast<const float4*>(out)[i];
    float4 b = reinterpret_cast<const float4*>(p)[i];
    a.x += b.x; a.y += b.y; a.z += b.z; a.w += b.w;
    reinterpret_cast<float4*>(out)[i] = a;
}

__device__ __forceinline__ void gload16(const void* g, void* s) {
    auto gp = reinterpret_cast<const __attribute__((address_space(1))) u32*>(
        reinterpret_cast<uintptr_t>(g));
    auto sp = reinterpret_cast<__attribute__((address_space(3))) u32*>(
        reinterpret_cast<uintptr_t>(s));
    __builtin_amdgcn_global_load_lds(gp, sp, 16, 0, 0);
}

#define BK 32

// LDS rows of 64B; swizzle slot ^= (row>>1)&3 (verified: 0 bank conflicts).
__device__ __forceinline__ int swz(int a) { return a ^ (((a >> 7) & 3) << 4); }

template <int ROWS, int THREADS>
__device__ __forceinline__ void stage_tile(const u16* g, size_t krow_b, size_t kb0,
                                           char* s, int t) {
#pragma unroll
    for (int rnd = 0; rnd < ROWS * 64 / (THREADS * 16); rnd++) {
        int o = t * 16 + rnd * THREADS * 16;
        int os = swz(o);
        int row = o >> 6, kb = os & 63;
        gload16((const char*)g + (size_t)row * krow_b + kb0 + kb, s + o);
    }
}

template <int N>
__device__ __forceinline__ void vm_wait() {
    if constexpr (N == 0) asm volatile("s_waitcnt vmcnt(0)" ::: "memory");
    else if constexpr (N == 3) asm volatile("s_waitcnt vmcnt(3)" ::: "memory");
    else if constexpr (N == 4) asm volatile("s_waitcnt vmcnt(4)" ::: "memory");
    else if constexpr (N == 6) asm volatile("s_waitcnt vmcnt(6)" ::: "memory");
    else if constexpr (N == 8) asm volatile("s_waitcnt vmcnt(8)" ::: "memory");
    else static_assert(N == 0, "unsupported vmcnt");
}

// ---- up-proj body: 256x128 tile, 8 waves (4x2), 3-ring counted vmcnt ----
__device__ void up_body(char* smem, int bx, int by,
                        const u16* __restrict__ A, const u16* __restrict__ B,
                        u16* __restrict__ act, int M, int N, int K) {
    constexpr int LPS = 3;   // (256+128)*64 / (512*16)
    const int t = threadIdx.x;
    const int lane = t & 63;
    const int wave = t >> 6;
    const int wr = wave >> 1, wc = wave & 1;   // 4x2 waves, WM=WN=64
    const int ro = lane & 15;
    const int ko = (lane >> 4) * 16;
    const int m0 = by * 256, n0 = bx * 128;

    f32x4 acc[4][4];
#pragma unroll
    for (int i = 0; i < 4; i++)
#pragma unroll
        for (int j = 0; j < 4; j++) acc[i][j] = (f32x4){0.f, 0.f, 0.f, 0.f};

    const size_t krow = (size_t)K * 2;
    const u16* Ab = A + (size_t)m0 * K;
    const u16* Bb = B + (size_t)n0 * K;
    char* smA = smem;
    char* smB = smem + 49152;

    auto stage_all = [&](int b, int k0) {
        size_t kb0 = (size_t)k0 * 2;
        stage_tile<256, 512>(Ab, krow, kb0, smA + b * 16384, t);
        stage_tile<128, 512>(Bb, krow, kb0, smB + b * 8192, t);
    };

    const int NU = K / BK;
    stage_all(0, 0);
    stage_all(1, BK);

    int cur = 0, pre = 2;
    for (int u = 0; u < NU; ++u) {
        if (u + 2 < NU) stage_all(pre, (u + 2) * BK);
        if (u + 2 < NU) vm_wait<2 * LPS>();
        else if (u + 1 < NU) vm_wait<LPS>();
        else vm_wait<0>();
        __builtin_amdgcn_s_barrier();

        const char* Ac = smA + cur * 16384;
        const char* Bc = smB + cur * 8192;
        bf16x8 fa[4], fb[4];
#pragma unroll
        for (int i = 0; i < 4; i++)
            fa[i] = *reinterpret_cast<const bf16x8*>(Ac + swz((wr * 64 + i * 16 + ro) * 64 + ko));
#pragma unroll
        for (int j = 0; j < 4; j++)
            fb[j] = *reinterpret_cast<const bf16x8*>(Bc + swz((wc * 64 + j * 16 + ro) * 64 + ko));
#pragma unroll
        for (int i = 0; i < 4; i++)
#pragma unroll
            for (int j = 0; j < 4; j++)
                acc[i][j] = __builtin_amdgcn_mfma_f32_16x16x32_bf16(fa[i], fb[j],
                                                                    acc[i][j], 0, 0, 0);
        __builtin_amdgcn_s_barrier();
        cur = (cur == 2) ? 0 : cur + 1;
        pre = (pre == 2) ? 0 : pre + 1;
    }

#pragma unroll
    for (int i = 0; i < 4; i++)
#pragma unroll
        for (int j = 0; j < 4; j++) {
            int col = n0 + wc * 64 + j * 16 + ro;
            int rbase = m0 + wr * 64 + i * 16 + (lane >> 4) * 4;
#pragma unroll
            for (int r = 0; r < 4; r++) {
                float v = acc[i][j][r];
                float s = v / (1.f + __expf(-v));
                act[(size_t)(rbase + r) * N + col] = f2bf(s);
            }
        }
}

// ---- sim body: 64x128 tile, 8 waves (2x4), 2-phase, SPLIT hi/lo ----
__device__ void sim_body(char* smem, int bx, int by,
                         const u16* __restrict__ Ahi, const u16* __restrict__ Alo,
                         const u16* __restrict__ Bhi, const u16* __restrict__ Blo,
                         float* __restrict__ C, int M, int N, int K) {
    const int t = threadIdx.x;
    const int lane = t & 63;
    const int wave = t >> 6;
    const int wr = wave >> 2, wc = wave & 3;   // 2x4 waves, WM=WN=32
    const int ro = lane & 15;
    const int ko = (lane >> 4) * 16;
    const int m0 = by * 64, n0 = bx * 128;

    f32x4 acc[2][2];
#pragma unroll
    for (int i = 0; i < 2; i++)
#pragma unroll
        for (int j = 0; j < 2; j++) acc[i][j] = (f32x4){0.f, 0.f, 0.f, 0.f};

    const size_t krow = (size_t)K * 2;
    const u16* Ahb = Ahi + (size_t)m0 * K;
    const u16* Alb = Alo + (size_t)m0 * K;
    const u16* Bhb = Bhi + (size_t)n0 * K;
    const u16* Blb = Blo + (size_t)n0 * K;
    char* smA = smem;
    char* smB = smem + 16384;

    auto stage_all = [&](int b, int k0) {
        size_t kb0 = (size_t)k0 * 2;
        {
            int sel = t >> 8, tt = t & 255;
            const u16* g = sel ? Alb : Ahb;
            int o = tt * 16;
            int os = swz(o);
            gload16((const char*)g + (size_t)(o >> 6) * krow + kb0 + (os & 63),
                    smA + b * 8192 + sel * 4096 + o);
        }
        {
            int o = t * 16, os = swz(o);
            gload16((const char*)Bhb + (size_t)(o >> 6) * krow + kb0 + (os & 63),
                    smB + b * 16384 + o);
        }
        {
            int o = t * 16, os = swz(o);
            gload16((const char*)Blb + (size_t)(o >> 6) * krow + kb0 + (os & 63),
                    smB + b * 16384 + 8192 + o);
        }
    };

    stage_all(0, 0);
    __syncthreads();
    int cur = 0;

    for (int k0 = 0; k0 < K; k0 += BK) {
        if (k0 + BK < K) stage_all(cur ^ 1, k0 + BK);
        const char* Ac = smA + cur * 8192;
        const char* Bc = smB + cur * 16384;
        bf16x8 fa[2], fal[2], fb[2], fbl[2];
#pragma unroll
        for (int i = 0; i < 2; i++) {
            int a = swz((wr * 32 + i * 16 + ro) * 64 + ko);
            fa[i] = *reinterpret_cast<const bf16x8*>(Ac + a);
            fal[i] = *reinterpret_cast<const bf16x8*>(Ac + 4096 + a);
        }
#pragma unroll
        for (int j = 0; j < 2; j++) {
            int a = swz((wc * 32 + j * 16 + ro) * 64 + ko);
            fb[j] = *reinterpret_cast<const bf16x8*>(Bc + a);
            fbl[j] = *reinterpret_cast<const bf16x8*>(Bc + 8192 + a);
        }
#pragma unroll
        for (int i = 0; i < 2; i++)
#pragma unroll
            for (int j = 0; j < 2; j++) {
                acc[i][j] = __builtin_amdgcn_mfma_f32_16x16x32_bf16(fa[i], fb[j],
                                                                    acc[i][j], 0, 0, 0);
                acc[i][j] = __builtin_amdgcn_mfma_f32_16x16x32_bf16(fa[i], fbl[j],
                                                                    acc[i][j], 0, 0, 0);
                acc[i][j] = __builtin_amdgcn_mfma_f32_16x16x32_bf16(fal[i], fb[j],
                                                                    acc[i][j], 0, 0, 0);
            }
        __syncthreads();
        cur ^= 1;
    }

#pragma unroll
    for (int i = 0; i < 2; i++)
#pragma unroll
        for (int j = 0; j < 2; j++) {
            int col = n0 + wc * 32 + j * 16 + ro;
            int rbase = m0 + wr * 32 + i * 16 + (lane >> 4) * 4;
#pragma unroll
            for (int r = 0; r < 4; r++)
                C[(size_t)(rbase + r) * N + col] = acc[i][j][r];
        }
}

// Fused: blocks [0,256) = SIM (dispatched FIRST: sim blocks co-reside with
// the first up blocks and retire early -> up backfills = overlap, not tail),
// blocks [256,768) = up-proj (XCD-swizzled on ub = bid-256).
__global__ __launch_bounds__(512, 4) void up_sim(
    const u16* __restrict__ hid_hi, const u16* __restrict__ hid_lo,
    const u16* __restrict__ wup,
    const u16* __restrict__ weff_hi, const u16* __restrict__ weff_lo,
    u16* __restrict__ act, float* __restrict__ Simb) {
    __shared__ char smem[73728];
    int bid = blockIdx.x;
    if (bid < 256) {
        int sb = bid;                            // grid 4 x 64
        sim_body(smem, sb & 3, sb >> 2, hid_hi, hid_lo, weff_hi, weff_lo, Simb,
                 TOKENS, QDIM, HDIM);
    } else {
        int ub = bid - 256;
        int b2 = (ub & 7) * 64 + (ub >> 3);      // bijective XCD remap over 512
        up_body(smem, b2 % 32, b2 / 32, hid_hi, wup, act, TOKENS, IDIM, HDIM);
    }
}

// ---- 3-ring counted-vmcnt GEMM for the down projection ----
// z==0 writes v + ext (expst); z==1 writes v to Cout2 (added in reduce_add).
template <int TBM, int TBN, int WVM, int WVN, int KCHUNKS>
__global__ __launch_bounds__(WVM * WVN * 64) void gemm_p3(
    const u16* __restrict__ A, const u16* __restrict__ B,
    float* __restrict__ Cout, float* __restrict__ Cout2,
    const float* __restrict__ ext, int M, int N, int K) {
    constexpr int THREADS = WVM * WVN * 64;
    constexpr int WM = TBM / WVM, WN = TBN / WVN;
    constexpr int FM = WM / 16, FN = WN / 16;
    constexpr int LPS = (TBM + TBN) * 64 / (THREADS * 16);
    __shared__ u16 As[3][TBM * BK];
    __shared__ u16 Bs[3][TBN * BK];
    const int t = threadIdx.x;
    const int lane = t & 63;
    const int wave = t >> 6;
    const int wr = wave / WVN, wc = wave % WVN;
    const int ro = lane & 15;
    const int ko = (lane >> 4) * 16;

    int bx = blockIdx.x, by = blockIdx.y;
    {
        int gx = gridDim.x;
        int n = gx * gridDim.y;      // divisible by 8
        int bid = by * gx + bx;
        int q = n >> 3;
        bid = (bid & 7) * q + (bid >> 3);
        bx = bid % gx; by = bid / gx;
    }
    const int m0 = by * TBM;
    const int n0 = bx * TBN;
    const int klen = K / KCHUNKS;
    const int z = (KCHUNKS > 1) ? blockIdx.z : 0;
    const int koff = z * klen;
    const int NU = klen / BK;

    f32x4 acc[FM][FN];
#pragma unroll
    for (int i = 0; i < FM; i++)
#pragma unroll
        for (int j = 0; j < FN; j++) acc[i][j] = (f32x4){0.f, 0.f, 0.f, 0.f};

    const size_t krow = (size_t)K * 2;
    const u16* Ab = A + (size_t)m0 * K;
    const u16* Bb = B + (size_t)n0 * K;

    auto stage_all = [&](int b, int k0) {
        size_t kb0 = (size_t)k0 * 2;
        stage_tile<TBM, THREADS>(Ab, krow, kb0, (char*)As[b], t);
        stage_tile<TBN, THREADS>(Bb, krow, kb0, (char*)Bs[b], t);
    };

    stage_all(0, koff);
    stage_all(1, koff + BK);

    int cur = 0, pre = 2;
    for (int u = 0; u < NU; ++u) {
        int k0 = koff + u * BK;
        if (u + 2 < NU) stage_all(pre, k0 + 2 * BK);
        if (u + 2 < NU) vm_wait<2 * LPS>();
        else if (u + 1 < NU) vm_wait<LPS>();
        else vm_wait<0>();
        __builtin_amdgcn_s_barrier();

        const u16* Ac = As[cur];
        const u16* Bc = Bs[cur];
        bf16x8 fa[FM], fb[FN];
#pragma unroll
        for (int i = 0; i < FM; i++)
            fa[i] = *reinterpret_cast<const bf16x8*>(
                (const char*)Ac + swz((wr * WM + i * 16 + ro) * 64 + ko));
#pragma unroll
        for (int j = 0; j < FN; j++)
            fb[j] = *reinterpret_cast<const bf16x8*>(
                (const char*)Bc + swz((wc * WN + j * 16 + ro) * 64 + ko));
#pragma unroll
        for (int i = 0; i < FM; i++)
#pragma unroll
            for (int j = 0; j < FN; j++)
                acc[i][j] = __builtin_amdgcn_mfma_f32_16x16x32_bf16(fa[i], fb[j],
                                                                    acc[i][j], 0, 0, 0);
        __builtin_amdgcn_s_barrier();
        cur = (cur == 2) ? 0 : cur + 1;
        pre = (pre == 2) ? 0 : pre + 1;
    }

#pragma unroll
    for (int i = 0; i < FM; i++)
#pragma unroll
        for (int j = 0; j < FN; j++) {
            int col = n0 + wc * WN + j * 16 + ro;
            int rbase = m0 + wr * WM + i * 16 + (lane >> 4) * 4;
#pragma unroll
            for (int r = 0; r < 4; r++) {
                float v = acc[i][j][r];
                size_t off = (size_t)(rbase + r) * N + col;
                if (z == 0) Cout[off] = v + ext[off];
                else Cout2[off] = v;
            }
        }
}

// Rank of value v (lane l) among 64 values in LDS, JAX top_k tie order.
__device__ __forceinline__ int rank64(const float* base, float v, int l) {
    const float4* gv = reinterpret_cast<const float4*>(base);
    int rank = 0;
#pragma unroll
    for (int n = 0; n < 16; n++) {
        float4 o = gv[n];
        int b = n * 4;
        rank += (o.x > v) || (o.x == v && (b + 0) < l);
        rank += (o.y > v) || (o.y == v && (b + 1) < l);
        rank += (o.z > v) || (o.z == v && (b + 2) < l);
        rank += (o.w > v) || (o.w == v && (b + 3) < l);
    }
    return rank;
}

// Fused router + expert gather: one token per 512-thread block.
// T14: the hid row load (independent of all router results) is issued at
// kernel TOP so its HBM/L2 latency hides under the 4 router barrier phases
// (the compiler cannot hoist global loads across __syncthreads itself).
__global__ __launch_bounds__(512) void router_gather(
    const float* __restrict__ Simb, const u16* __restrict__ hid_bf,
    const u32* __restrict__ de_f8, const u32* __restrict__ ue_f8,
    float* __restrict__ expst) {
    __shared__ float sims[QDIM];
    __shared__ float topv[8][TOPK];
    __shared__ int topi[8][TOPK];
    __shared__ float pv[NHEADS][64];
    __shared__ float st8[NHEADS][TOPK];
    __shared__ int sid8[NHEADS][TOPK];
    __shared__ float gate8[NHEADS][TOPK];
    __shared__ float wks[NHEADS][TOPK];
    __shared__ float red[8][256];

    const int tok = blockIdx.x;
    const int tid = threadIdx.x;
    const int w = tid >> 6, l = tid & 63;

    // hoisted hid row load (used in dot phase by all waves)
    u16x8 hv0, hv1;
    {
        const u16* hrow = hid_bf + (size_t)tok * HDIM + l * 16;
        hv0 = *reinterpret_cast<const u16x8*>(hrow);
        hv1 = *reinterpret_cast<const u16x8*>(hrow + 8);
    }

    sims[tid] = Simb[(size_t)tok * QDIM + tid];
    __syncthreads();

    {   // per-group rank
        float v = sims[w * 64 + l];
        int rank = rank64(sims + w * 64, v, l);
        if (rank < TOPK) { topv[w][rank] = v; topi[w][rank] = l; }
    }
    __syncthreads();

    if (w < NHEADS) pv[w][l] = topv[w][l >> 3] + topv[4 + w][l & 7];
    __syncthreads();

    if (w < NHEADS) {
        float v = pv[w][l];
        int rank = rank64(pv[w], v, l);
        if (rank < TOPK) {
            st8[w][rank] = v;
            sid8[w][rank] = topi[w][l >> 3] * NKEYS + topi[4 + w][l & 7];
        }
    }
    __syncthreads();

    if (tid < NHEADS * TOPK) {
        int h = tid >> 3, r = tid & 7;
        float m0 = st8[h][0];
        float s = 0.f;
#pragma unroll
        for (int i = 0; i < TOPK; i++) s += __expf(st8[h][i] - m0);
        gate8[h][r] = __expf(st8[h][r] - m0) / s;
    }
    __syncthreads();

    {   // dot phase: wave w -> head w>>1, experts kq..kq+3
        const int head = w >> 1, kq = (w & 1) * 4;
        float h16[16];
#pragma unroll
        for (int t2 = 0; t2 < 8; t2++) {
            h16[t2] = bf2f(hv0[t2]);
            h16[8 + t2] = bf2f(hv1[t2]);
        }
        int eid[4];
        float gt[4];
#pragma unroll
        for (int j = 0; j < 4; j++) {
            eid[j] = sid8[head][kq + j];
            gt[j] = gate8[head][kq + j];
        }
        u32x4 dv[4];
#pragma unroll
        for (int j = 0; j < 4; j++)
            dv[j] = *reinterpret_cast<const u32x4*>(de_f8 + (size_t)eid[j] * 256 + l * 4);
        float dot[4];
#pragma unroll
        for (int j = 0; j < 4; j++) {
            float s = 0.f;
#pragma unroll
            for (int w2 = 0; w2 < 4; w2++) {
                u32 word = dv[j][w2];
                f32x2 lo = __builtin_amdgcn_cvt_pk_f32_fp8(word, false);
                f32x2 hi = __builtin_amdgcn_cvt_pk_f32_fp8(word, true);
                s += h16[w2 * 4 + 0] * lo[0] + h16[w2 * 4 + 1] * lo[1] +
                     h16[w2 * 4 + 2] * hi[0] + h16[w2 * 4 + 3] * hi[1];
            }
            dot[j] = s;
        }
#pragma unroll
        for (int m = 32; m; m >>= 1)
#pragma unroll
            for (int j = 0; j < 4; j++) dot[j] += __shfl_xor(dot[j], m, 64);
        if (l < 4) {
            float x = dot[l] * gt[l];
            wks[head][kq + l] = x / (1.f + __expf(-x));
        }
    }
    __syncthreads();

    {   // acc phase: wave w -> quarter q=w>>1, expert half hf=w&1
        const int q = w >> 1, hf = w & 1;
        float acc0 = 0.f, acc1 = 0.f, acc2 = 0.f, acc3 = 0.f;
        const u32* ubase = ue_f8 + q * 64 + l;
#pragma unroll
        for (int m = 0; m < 16; m++) {
            int mm = hf * 16 + m;
            int h = mm >> 3, k = mm & 7;
            int e = sid8[h][k];
            float wk = wks[h][k];
            u32 u = ubase[(size_t)e * 256];
            f32x2 lo = __builtin_amdgcn_cvt_pk_f32_fp8(u, false);
            f32x2 hi = __builtin_amdgcn_cvt_pk_f32_fp8(u, true);
            acc0 += wk * lo[0]; acc1 += wk * lo[1];
            acc2 += wk * hi[0]; acc3 += wk * hi[1];
        }
        *reinterpret_cast<float4*>(&red[w][l * 4]) = make_float4(acc0, acc1, acc2, acc3);
    }
    __syncthreads();

    {   // final: out quarter q = red[2q] + red[2q+1]
        int d = tid * 2;
        int qq = d >> 8, dq = d & 255;
        float2 a = *reinterpret_cast<float2*>(&red[2 * qq][dq]);
        float2 b = *reinterpret_cast<float2*>(&red[2 * qq + 1][dq]);
        float2 o;
        o.x = a.x + b.x;
        o.y = a.y + b.y;
        *reinterpret_cast<float2*>(expst + (size_t)tok * HDIM + d) = o;
    }
}

extern "C" void kernel_launch(void* const* d_in, const int* in_sizes, int n_in,
                              void* d_out, int out_size, void* d_ws, size_t ws_size,
                              hipStream_t stream) {
    const float* hidden = (const float*)d_in[0];
    const float* W_up = (const float*)d_in[1];
    const float* W_down = (const float*)d_in[2];
    const float* W_q = (const float*)d_in[3];
    const float* keys = (const float*)d_in[4];
    const float* down_embed = (const float*)d_in[5];
    const float* up_embed = (const float*)d_in[6];
    float* out = (float*)d_out;

    char* ws = (char*)d_ws;
    size_t off = 0;
    auto alloc = [&](size_t bytes) {
        void* p = ws + off;
        off += (bytes + 255) & ~(size_t)255;
        return p;
    };
    u16* hid_hi = (u16*)alloc((size_t)TOKENS * HDIM * 2);
    // hid_lo + Simb (16.78 MB) are dead after router_gather; down K-chunk-1
    // partial overlays them.
    u16* hid_lo = (u16*)alloc((size_t)TOKENS * HDIM * 2);
    float* Simb = (float*)alloc((size_t)TOKENS * QDIM * 4);
    float* partial = (float*)hid_lo;
    u16* weff_hi = (u16*)alloc((size_t)QDIM * HDIM * 2);
    u16* weff_lo = (u16*)alloc((size_t)QDIM * HDIM * 2);
    u16* wup = (u16*)alloc((size_t)IDIM * HDIM * 2);
    u16* wdn = (u16*)alloc((size_t)HDIM * IDIM * 2);
    u16* act = (u16*)alloc((size_t)TOKENS * IDIM * 2);
    u32* de_f8 = (u32*)alloc((size_t)4096 * HDIM);
    u32* ue_f8 = (u32*)alloc((size_t)4096 * HDIM);
    float* expst = (float*)alloc((size_t)TOKENS * HDIM * 4);

    cvt_all<<<(CVT_TOT + 255) / 256, 256, 0, stream>>>(
        hidden, W_up, W_down, down_embed, up_embed,
        hid_hi, hid_lo, wup, wdn, de_f8, ue_f8);
    weff_kernel<<<64, 256, 0, stream>>>(keys, W_q, weff_hi, weff_lo);

    // fused sim (256, first -> overlaps) + up-proj (512)
    up_sim<<<768, 512, 0, stream>>>(hid_hi, hid_lo, wup, weff_hi, weff_lo, act, Simb);

    router_gather<<<TOKENS, 512, 0, stream>>>(Simb, hid_hi, de_f8, ue_f8, expst);

    // down proj: 128x128 tile, 3-ring counted-vmcnt, K-split x2, XCD-swz
    gemm_p3<128, 128, 2, 2, 2>
        <<<dim3(HDIM / 128, TOKENS / 128, 2), 256, 0, stream>>>(
        act, wdn, out, partial, expst, TOKENS, HDIM, IDIM);
    reduce_add<<<(TOKENS * HDIM / 4 + 255) / 256, 256, 0, stream>>>(out, partial,
                                                                    TOKENS * HDIM / 4);
}